// Round 1
// baseline (484.538 us; speedup 1.0000x reference)
//
#include <hip/hip_runtime.h>
#include <hip/hip_bf16.h>

typedef __bf16 bf16x8 __attribute__((ext_vector_type(8)));
typedef float f32x4 __attribute__((ext_vector_type(4)));

#define NB 64
#define NN 512
#define NC 64
#define NH 8
#define NR 17
#define NE 21
#define MR 8704   /* NN*NR */
#define BCC 4096  /* NB*NC */

__device__ __forceinline__ float bf2f(__hip_bfloat16 v) { return __bfloat162float(v); }

__device__ __forceinline__ void gload_lds16(const void* g, void* l) {
  __builtin_amdgcn_global_load_lds(
      (const __attribute__((address_space(1))) void*)g,
      (__attribute__((address_space(3))) void*)l, 16, 0, 0);
}

// ---------------- pack assignment [m][n][r] -> A2 [(m*17+r)][n] bf16 ----------------
__global__ __launch_bounds__(256) void pack_A(const float* __restrict__ a,
                                              __hip_bfloat16* __restrict__ A2) {
  __shared__ __hip_bfloat16 T[NR * 136];
  const int m = blockIdx.y;
  const int n0 = blockIdx.x * 128;
  const float* src = a + (size_t)m * (NN * NR) + (size_t)n0 * NR;
  for (int t = threadIdx.x; t < 128 * NR; t += 256) {
    int i = t / NR;
    int r = t - i * NR;
    T[r * 136 + i] = __float2bfloat16(src[t]);
  }
  __syncthreads();
  for (int t = threadIdx.x; t < NR * 128; t += 256) {
    int r = t >> 7;
    int i = t & 127;
    A2[((size_t)m * NR + r) * NN + n0 + i] = T[r * 136 + i];
  }
}

// ---------------- pack x [b][n][c] -> XT [(b*64+c)][n] bf16 ----------------
__global__ __launch_bounds__(256) void pack_X(const float* __restrict__ x,
                                              __hip_bfloat16* __restrict__ XT) {
  __shared__ __hip_bfloat16 T[NC * 136];
  const int b = blockIdx.y;
  const int n0 = blockIdx.x * 128;
  const float* src = x + (size_t)b * (NN * NC) + (size_t)n0 * NC;
  for (int t = threadIdx.x; t < 128 * NC; t += 256) {
    int i = t >> 6;
    int c = t & 63;
    T[c * 136 + i] = __float2bfloat16(src[t]);
  }
  __syncthreads();
  for (int t = threadIdx.x; t < NC * 128; t += 256) {
    int c = t >> 7;
    int i = t & 127;
    XT[((size_t)b * NC + c) * NN + n0 + i] = T[c * 136 + i];
  }
}

// ---------------- pre_kv GEMM: C[i=(m,r)][j=(b,c)] = sum_n A2[i][n]*XT[j][n] ----------------
// 128x128 tile, BK=64, 4 waves, 16x16x32 bf16 MFMA, XOR-swizzled LDS via global_load_lds(16B)
__global__ __launch_bounds__(256) void gemm_prekv(const __hip_bfloat16* __restrict__ A2,
                                                  const __hip_bfloat16* __restrict__ XT,
                                                  __hip_bfloat16* __restrict__ pkv) {
  __shared__ char As[16384];
  __shared__ char Bs[16384];
  const int tid = threadIdx.x;
  const int wave = tid >> 6;
  const int lane = tid & 63;
  const int rowBase = blockIdx.y * 128;   // over 8704 (m,r)
  const int colBase = blockIdx.x * 128;   // over 4096 (b,c)
  const int wrow0 = (wave >> 1) * 64;
  const int wcol0 = (wave & 1) * 64;

  const int lrow8 = lane >> 3;     // row within 8-row staging group
  const int gslot = lane & 7;      // 16B granule slot in LDS
  const int gsrc = gslot ^ lrow8;  // source granule (rows of group are 8-aligned)

  f32x4 acc[4][4];
#pragma unroll
  for (int i = 0; i < 4; ++i)
#pragma unroll
    for (int j = 0; j < 4; ++j) acc[i][j] = (f32x4)0.0f;

  const int fr = lane & 15;
  const int kg = lane >> 4;

  for (int kt = 0; kt < NN; kt += 64) {
#pragma unroll
    for (int cc = 0; cc < 4; ++cc) {
      const int r0 = wave * 32 + cc * 8;  // wave-uniform
      gload_lds16(A2 + ((size_t)(rowBase + r0 + lrow8) * NN + kt + gsrc * 8), As + r0 * 128);
      gload_lds16(XT + ((size_t)(colBase + r0 + lrow8) * NN + kt + gsrc * 8), Bs + r0 * 128);
    }
    __syncthreads();
#pragma unroll
    for (int kk = 0; kk < 2; ++kk) {
      bf16x8 av[4], bv[4];
#pragma unroll
      for (int mi = 0; mi < 4; ++mi) {
        const int row = wrow0 + mi * 16 + fr;
        const int slot = (kk * 4 + kg) ^ (row & 7);
        av[mi] = *(const bf16x8*)(As + row * 128 + slot * 16);
      }
#pragma unroll
      for (int ni = 0; ni < 4; ++ni) {
        const int row = wcol0 + ni * 16 + fr;
        const int slot = (kk * 4 + kg) ^ (row & 7);
        bv[ni] = *(const bf16x8*)(Bs + row * 128 + slot * 16);
      }
#pragma unroll
      for (int mi = 0; mi < 4; ++mi)
#pragma unroll
        for (int ni = 0; ni < 4; ++ni)
          acc[mi][ni] =
              __builtin_amdgcn_mfma_f32_16x16x32_bf16(av[mi], bv[ni], acc[mi][ni], 0, 0, 0);
    }
    __syncthreads();
  }

  // epilogue: D lane map col=lane&15, row=(lane>>4)*4+reg  -> pkv[b][m][r][c] bf16
  const int rq = lane >> 4;
#pragma unroll
  for (int mi = 0; mi < 4; ++mi) {
#pragma unroll
    for (int ni = 0; ni < 4; ++ni) {
#pragma unroll
      for (int reg = 0; reg < 4; ++reg) {
        const int gi = rowBase + wrow0 + mi * 16 + rq * 4 + reg;
        const int gj = colBase + wcol0 + ni * 16 + fr;
        const unsigned m = (unsigned)gi / 17u;
        const unsigned r = (unsigned)gi - m * 17u;
        const int bb = gj >> 6;
        const int c = gj & 63;
        pkv[(((size_t)bb * NN + m) * NR + r) * NC + c] = __float2bfloat16(acc[mi][ni][reg]);
      }
    }
  }
}

// ---------------- fused attention: 8 waves/block, one token per wave ----------------
#define SM_WQT 0
#define SM_WK 8192
#define SM_WVT 16384
#define SM_WPT 24576
#define SM_W1T 32768
#define SM_W2T 35456
#define SM_RB 52864
#define SM_B2 53408
#define SM_BP 53952
#define SM_B1 54208
#define SM_WEND 54464
#define TOKSZ 8512
#define SMEM_TOTAL (SM_WEND + 8 * TOKSZ) /* 122560 */

__global__ __launch_bounds__(512) void attn_fused(
    const float* __restrict__ x, const float* __restrict__ ext,
    const __hip_bfloat16* __restrict__ pkv, const float* __restrict__ Wq,
    const float* __restrict__ Wkv, const float* __restrict__ rb, const float* __restrict__ W1,
    const float* __restrict__ b1, const float* __restrict__ W2, const float* __restrict__ b2,
    const float* __restrict__ Wp, const float* __restrict__ bp, const int* __restrict__ mask,
    float* __restrict__ out) {
  extern __shared__ char smem[];
  __hip_bfloat16* WqT = (__hip_bfloat16*)(smem + SM_WQT);  // [c][i] = Wq[i][c]
  __hip_bfloat16* Wk = (__hip_bfloat16*)(smem + SM_WK);    // [i][c] = Wkv[i][c]
  __hip_bfloat16* WvT = (__hip_bfloat16*)(smem + SM_WVT);  // [c][i] = Wkv[64+i][c]
  __hip_bfloat16* WpT = (__hip_bfloat16*)(smem + SM_WPT);  // [i][j] = Wp[j][i]
  __hip_bfloat16* W1T = (__hip_bfloat16*)(smem + SM_W1T);  // [e][h] = W1[h][e]
  __hip_bfloat16* W2T = (__hip_bfloat16*)(smem + SM_W2T);  // [hh][o] = W2[o][hh], stride 136
  float* rbs = (float*)(smem + SM_RB);
  float* b2s = (float*)(smem + SM_B2);
  float* bps = (float*)(smem + SM_BP);
  float* b1s = (float*)(smem + SM_B1);

  const int tid = threadIdx.x;
  for (int t = tid; t < 4096; t += 512) {
    const int i = t >> 6, c = t & 63;
    WqT[c * 64 + i] = __float2bfloat16(Wq[t]);
    Wk[t] = __float2bfloat16(Wkv[t]);
    WvT[c * 64 + i] = __float2bfloat16(Wkv[4096 + t]);
    WpT[c * 64 + i] = __float2bfloat16(Wp[t]);
  }
  for (int t = tid; t < NC * NE; t += 512) {
    const int h = t / NE, e = t - h * NE;
    W1T[e * 64 + h] = __float2bfloat16(W1[t]);
  }
  for (int t = tid; t < 136 * 64; t += 512) {
    const int o = t >> 6, hh = t & 63;
    W2T[hh * 136 + o] = __float2bfloat16(W2[t]);
  }
  if (tid < 136) {
    rbs[tid] = rb[tid];
    b2s[tid] = b2[tid];
  }
  if (tid < 64) {
    bps[tid] = bp[tid];
    b1s[tid] = b1[tid];
  }

  const int wave = tid >> 6;
  const int lane = tid & 63;
  const int token = blockIdx.x * 8 + wave;  // = b*512 + m
  const int mm = token & (NN - 1);

  char* sc = smem + SM_WEND + wave * TOKSZ;
  float* xs = (float*)sc;
  float* exts = xs + 64;
  float* qs = exts + 24;
  float* qws = qs + 64;    // [8][68]
  float* hids = qws + 8 * 68;
  float* lg = hids + 64;   // [144]
  float* ts = lg + 144;    // [8][68]
  float* o1s = ts + 8 * 68;
  __hip_bfloat16* pkvs = (__hip_bfloat16*)(o1s + 64);  // [17][72] bf16

  // S1: per-token loads
  xs[lane] = x[(size_t)token * NC + lane];
  if (lane < NE) exts[lane] = ext[(size_t)token * NE + lane];
#pragma unroll
  for (int r = 0; r < NR; ++r)
    pkvs[r * 72 + lane] = pkv[((size_t)token * NR + r) * NC + lane];
  __syncthreads();

  // S2: q[i] and hidden (ext MLP layer 1)
  {
    float a = 0.f, h = b1s[lane];
#pragma unroll 8
    for (int c = 0; c < 64; ++c) a += xs[c] * bf2f(WqT[c * 64 + lane]);
#pragma unroll
    for (int e = 0; e < NE; ++e) h += exts[e] * bf2f(W1T[e * 64 + lane]);
    qs[lane] = a;
    hids[lane] = fmaxf(h, 0.f);
  }
  __syncthreads();

  // S3: qw[h][c] = sum_d q[h*8+d] * Wk[h*8+d][c]
#pragma unroll
  for (int h = 0; h < NH; ++h) {
    float a = 0.f;
#pragma unroll
    for (int d = 0; d < 8; ++d) a += qs[h * 8 + d] * bf2f(Wk[(h * 8 + d) * 64 + lane]);
    qws[h * 68 + lane] = a;
  }
  __syncthreads();

  // S4: logits[o=(h*17+r)] = scale*<pkv[r,:],qw[h,:]> + rb[o] + 0.01*ei[o]; mask -> -1e30
#pragma unroll
  for (int p = 0; p < 3; ++p) {
    const int o = lane + p * 64;
    if (o < NH * NR) {
      const int h = o / NR;
      const int r = o - h * NR;
      float ei = b2s[o];
#pragma unroll 8
      for (int hh = 0; hh < 64; ++hh) ei += hids[hh] * bf2f(W2T[hh * 136 + o]);
      float s = 0.f;
#pragma unroll 8
      for (int c = 0; c < 64; ++c) s += bf2f(pkvs[r * 72 + c]) * qws[h * 68 + c];
      float lgv = 0.35355339059327373f * s + rbs[o] + 0.01f * ei;
      if (mask[mm * NR + r] != 0) lgv = -1e30f;
      lg[o] = lgv;
    }
  }
  __syncthreads();

  // S5: softmax over r per h (8-lane group per h)
  {
    const int h = lane >> 3;
    const int kk = lane & 7;
    const float v0 = lg[h * NR + kk];
    const float v1 = lg[h * NR + kk + 8];
    const float v2 = (kk == 0) ? lg[h * NR + 16] : -3.0e38f;
    float mx = fmaxf(fmaxf(v0, v1), v2);
    mx = fmaxf(mx, __shfl_xor(mx, 1));
    mx = fmaxf(mx, __shfl_xor(mx, 2));
    mx = fmaxf(mx, __shfl_xor(mx, 4));
    const float e0 = __expf(v0 - mx);
    const float e1 = __expf(v1 - mx);
    const float e2 = (kk == 0) ? __expf(v2 - mx) : 0.f;
    float sum = e0 + e1 + e2;
    sum += __shfl_xor(sum, 1);
    sum += __shfl_xor(sum, 2);
    sum += __shfl_xor(sum, 4);
    const float inv = 1.f / sum;
    lg[h * NR + kk] = e0 * inv;
    lg[h * NR + kk + 8] = e1 * inv;
    if (kk == 0) lg[h * NR + 16] = e2 * inv;
  }
  __syncthreads();

  // S6: t[h][c] = sum_r p[h][r] * pkv[r][c]
#pragma unroll
  for (int h = 0; h < NH; ++h) {
    float a = 0.f;
#pragma unroll
    for (int r = 0; r < NR; ++r) a += lg[h * NR + r] * bf2f(pkvs[r * 72 + lane]);
    ts[h * 68 + lane] = a;
  }
  __syncthreads();

  // S7: o1[i] = sum_c t[h(i)][c] * Wv[i][c]
  {
    const int h = lane >> 3;
    float a = 0.f;
#pragma unroll 8
    for (int c = 0; c < 64; ++c) a += ts[h * 68 + c] * bf2f(WvT[c * 64 + lane]);
    o1s[lane] = a;
  }
  __syncthreads();

  // S8: out[j] = bp[j] + sum_i o1[i] * Wp[j][i]
  {
    float a = bps[lane];
#pragma unroll 8
    for (int i = 0; i < 64; ++i) a += o1s[i] * bf2f(WpT[i * 64 + lane]);
    out[(size_t)token * NC + lane] = a;
  }
}

extern "C" void kernel_launch(void* const* d_in, const int* in_sizes, int n_in, void* d_out,
                              int out_size, void* d_ws, size_t ws_size, hipStream_t stream) {
  const float* x = (const float*)d_in[0];
  const float* ext = (const float*)d_in[1];
  const float* assign = (const float*)d_in[2];
  const float* Wq = (const float*)d_in[3];
  const float* Wkv = (const float*)d_in[4];
  const float* rb = (const float*)d_in[5];
  const float* W1 = (const float*)d_in[6];
  const float* b1 = (const float*)d_in[7];
  const float* W2 = (const float*)d_in[8];
  const float* b2 = (const float*)d_in[9];
  const float* Wp = (const float*)d_in[10];
  const float* bp = (const float*)d_in[11];
  const int* mask = (const int*)d_in[12];
  float* out = (float*)d_out;

  char* ws = (char*)d_ws;
  __hip_bfloat16* A2 = (__hip_bfloat16*)(ws);                // 8,912,896 B
  __hip_bfloat16* XT = (__hip_bfloat16*)(ws + 8912896);      // 4,194,304 B
  __hip_bfloat16* PKV = (__hip_bfloat16*)(ws + 13107200);    // 71,303,168 B
  if (ws_size < (size_t)84410368) return;  // need ~80.5 MB scratch

  hipLaunchKernelGGL(pack_A, dim3(4, 512), dim3(256), 0, stream, assign, A2);
  hipLaunchKernelGGL(pack_X, dim3(4, 64), dim3(256), 0, stream, x, XT);
  hipLaunchKernelGGL(gemm_prekv, dim3(32, 68), dim3(256), 0, stream, A2, XT, PKV);
  hipFuncSetAttribute((const void*)attn_fused, hipFuncAttributeMaxDynamicSharedMemorySize,
                      SMEM_TOTAL);
  hipLaunchKernelGGL(attn_fused, dim3(4096), dim3(512), SMEM_TOTAL, stream, x, ext, PKV, Wq, Wkv,
                     rb, W1, b1, W2, b2, Wp, bp, mask, out);
}

// Round 2
// 269.225 us; speedup vs baseline: 1.7998x; 1.7998x over previous
//
#include <hip/hip_runtime.h>
#include <hip/hip_bf16.h>

typedef __bf16 bf16x8 __attribute__((ext_vector_type(8)));
typedef float f32x4 __attribute__((ext_vector_type(4)));

#define NN 512
#define NR 17

__device__ __forceinline__ __bf16 f2b(float f) {
  __hip_bfloat16 h = __float2bfloat16(f);
  return __builtin_bit_cast(__bf16, h);
}

__device__ __forceinline__ void gload_lds16(const void* g, void* l) {
  __builtin_amdgcn_global_load_lds(
      (const __attribute__((address_space(1))) void*)g,
      (__attribute__((address_space(3))) void*)l, 16, 0, 0);
}

// ---------------- pack assignment [m][n][r] -> A2 [(m*17+r)][n] bf16 ----------------
__global__ __launch_bounds__(256) void pack_A(const float* __restrict__ a,
                                              __hip_bfloat16* __restrict__ A2) {
  __shared__ __hip_bfloat16 T[NR * 136];
  const int m = blockIdx.y;
  const int n0 = blockIdx.x * 128;
  const float* src = a + (size_t)m * (NN * NR) + (size_t)n0 * NR;
  for (int t = threadIdx.x; t < 128 * NR; t += 256) {
    int i = t / NR;
    int r = t - i * NR;
    T[r * 136 + i] = __float2bfloat16(src[t]);
  }
  __syncthreads();
  for (int t = threadIdx.x; t < NR * 128; t += 256) {
    int r = t >> 7;
    int i = t & 127;
    A2[((size_t)m * NR + r) * NN + n0 + i] = T[r * 136 + i];
  }
}

// ---------------- pack x: XT [(b_local*64+c)][n] bf16 + XR [t_local][c] bf16 ----------------
__global__ __launch_bounds__(256) void pack_X(const float* __restrict__ x,
                                              __hip_bfloat16* __restrict__ XT,
                                              __hip_bfloat16* __restrict__ XR, int b0) {
  __shared__ __hip_bfloat16 T[64 * 136];
  const int by = blockIdx.y;
  const int n0 = blockIdx.x * 128;
  const float* src = x + ((size_t)(b0 + by) * NN + n0) * 64;
  for (int t = threadIdx.x; t < 128 * 64; t += 256) {
    int i = t >> 6;
    int c = t & 63;
    __hip_bfloat16 v = __float2bfloat16(src[t]);
    T[c * 136 + i] = v;
    XR[((size_t)by * NN + n0 + i) * 64 + c] = v;
  }
  __syncthreads();
  for (int t = threadIdx.x; t < 64 * 128; t += 256) {
    int c = t >> 7;
    int i = t & 127;
    XT[((size_t)by * 64 + c) * NN + n0 + i] = T[c * 136 + i];
  }
}

// ---------------- prep combined weights ----------------
__global__ __launch_bounds__(256) void prep_w(const float* __restrict__ Wq,
                                              const float* __restrict__ Wkv,
                                              const float* __restrict__ Wp,
                                              __hip_bfloat16* __restrict__ WQK,
                                              __hip_bfloat16* __restrict__ WVP) {
  const int base = blockIdx.x * 512 + threadIdx.x;
#pragma unroll
  for (int k = 0; k < 2; ++k) {
    const int idx = base + k * 256;
    {
      const int i = idx & 63, row = idx >> 6, h = row >> 6, c = row & 63;
      float a = 0.f;
#pragma unroll
      for (int d = 0; d < 8; ++d) a += Wq[(h * 8 + d) * 64 + i] * Wkv[(h * 8 + d) * 64 + c];
      WQK[idx] = __float2bfloat16(a * 0.35355339059327373f);
    }
    {
      const int hc = idx & 511, j = idx >> 9, h = hc >> 6, c = hc & 63;
      float a = 0.f;
#pragma unroll
      for (int d = 0; d < 8; ++d)
        a += Wkv[4096 + (h * 8 + d) * 64 + c] * Wp[j * 64 + (h * 8 + d)];
      WVP[idx] = __float2bfloat16(a);
    }
  }
}

// ---------------- pre_kv GEMM ----------------
__global__ __launch_bounds__(256) void gemm_prekv(const __hip_bfloat16* __restrict__ A2,
                                                  const __hip_bfloat16* __restrict__ XT,
                                                  __hip_bfloat16* __restrict__ pkv) {
  __shared__ char As[16384];
  __shared__ char Bs[16384];
  const int tid = threadIdx.x;
  const int wave = tid >> 6;
  const int lane = tid & 63;
  const int rowBase = blockIdx.y * 128;
  const int colBase = blockIdx.x * 128;
  const int wrow0 = (wave >> 1) * 64;
  const int wcol0 = (wave & 1) * 64;
  const int lrow8 = lane >> 3;
  const int gslot = lane & 7;
  const int gsrc = gslot ^ lrow8;

  f32x4 acc[4][4];
#pragma unroll
  for (int i = 0; i < 4; ++i)
#pragma unroll
    for (int j = 0; j < 4; ++j) acc[i][j] = (f32x4)0.0f;

  const int fr = lane & 15;
  const int kg = lane >> 4;

  for (int kt = 0; kt < NN; kt += 64) {
#pragma unroll
    for (int cc = 0; cc < 4; ++cc) {
      const int r0 = wave * 32 + cc * 8;
      gload_lds16(A2 + ((size_t)(rowBase + r0 + lrow8) * NN + kt + gsrc * 8), As + r0 * 128);
      gload_lds16(XT + ((size_t)(colBase + r0 + lrow8) * NN + kt + gsrc * 8), Bs + r0 * 128);
    }
    __syncthreads();
#pragma unroll
    for (int kk = 0; kk < 2; ++kk) {
      bf16x8 av[4], bv[4];
#pragma unroll
      for (int mi = 0; mi < 4; ++mi) {
        const int row = wrow0 + mi * 16 + fr;
        const int slot = (kk * 4 + kg) ^ (row & 7);
        av[mi] = *(const bf16x8*)(As + row * 128 + slot * 16);
      }
#pragma unroll
      for (int ni = 0; ni < 4; ++ni) {
        const int row = wcol0 + ni * 16 + fr;
        const int slot = (kk * 4 + kg) ^ (row & 7);
        bv[ni] = *(const bf16x8*)(Bs + row * 128 + slot * 16);
      }
#pragma unroll
      for (int mi = 0; mi < 4; ++mi)
#pragma unroll
        for (int ni = 0; ni < 4; ++ni)
          acc[mi][ni] =
              __builtin_amdgcn_mfma_f32_16x16x32_bf16(av[mi], bv[ni], acc[mi][ni], 0, 0, 0);
    }
    __syncthreads();
  }

  const int rq = lane >> 4;
#pragma unroll
  for (int mi = 0; mi < 4; ++mi) {
#pragma unroll
    for (int ni = 0; ni < 4; ++ni) {
#pragma unroll
      for (int reg = 0; reg < 4; ++reg) {
        const int gi = rowBase + wrow0 + mi * 16 + rq * 4 + reg;
        const int gj = colBase + wcol0 + ni * 16 + fr;
        const unsigned m = (unsigned)gi / 17u;
        const unsigned r = (unsigned)gi - m * 17u;
        const int bb = gj >> 6;
        const int c = gj & 63;
        pkv[(((size_t)bb * NN + m) * NR + r) * 64 + c] = __float2bfloat16(acc[mi][ni][reg]);
      }
    }
  }
}

// ---------------- qw GEMM: QW[t][(h*64+c)] = XR[t][:] @ WQK[(h*64+c)][:], K=64 ----------------
__global__ __launch_bounds__(256) void qw_gemm(const __hip_bfloat16* __restrict__ XR,
                                               const __hip_bfloat16* __restrict__ WQK,
                                               __hip_bfloat16* __restrict__ QW) {
  __shared__ char As[16384];
  __shared__ char Bs[16384];
  const int tid = threadIdx.x;
  const int wave = tid >> 6;
  const int lane = tid & 63;
  const int rowBase = blockIdx.y * 128;
  const int colBase = blockIdx.x * 128;
  const int wrow0 = (wave >> 1) * 64;
  const int wcol0 = (wave & 1) * 64;
  const int lrow8 = lane >> 3;
  const int gslot = lane & 7;
  const int gsrc = gslot ^ lrow8;
  const int fr = lane & 15;
  const int kg = lane >> 4;

  f32x4 acc[4][4];
#pragma unroll
  for (int i = 0; i < 4; ++i)
#pragma unroll
    for (int j = 0; j < 4; ++j) acc[i][j] = (f32x4)0.0f;

#pragma unroll
  for (int cc = 0; cc < 4; ++cc) {
    const int r0 = wave * 32 + cc * 8;
    gload_lds16(XR + ((size_t)(rowBase + r0 + lrow8) * 64 + gsrc * 8), As + r0 * 128);
    gload_lds16(WQK + ((size_t)(colBase + r0 + lrow8) * 64 + gsrc * 8), Bs + r0 * 128);
  }
  __syncthreads();
#pragma unroll
  for (int kk = 0; kk < 2; ++kk) {
    bf16x8 av[4], bv[4];
#pragma unroll
    for (int mi = 0; mi < 4; ++mi) {
      const int row = wrow0 + mi * 16 + fr;
      const int slot = (kk * 4 + kg) ^ (row & 7);
      av[mi] = *(const bf16x8*)(As + row * 128 + slot * 16);
    }
#pragma unroll
    for (int ni = 0; ni < 4; ++ni) {
      const int row = wcol0 + ni * 16 + fr;
      const int slot = (kk * 4 + kg) ^ (row & 7);
      bv[ni] = *(const bf16x8*)(Bs + row * 128 + slot * 16);
    }
#pragma unroll
    for (int mi = 0; mi < 4; ++mi)
#pragma unroll
      for (int ni = 0; ni < 4; ++ni)
        acc[mi][ni] =
            __builtin_amdgcn_mfma_f32_16x16x32_bf16(av[mi], bv[ni], acc[mi][ni], 0, 0, 0);
  }

  const int rq = lane >> 4;
#pragma unroll
  for (int mi = 0; mi < 4; ++mi)
#pragma unroll
    for (int ni = 0; ni < 4; ++ni)
#pragma unroll
      for (int reg = 0; reg < 4; ++reg) {
        const int gi = rowBase + wrow0 + mi * 16 + rq * 4 + reg;
        const int gj = colBase + wcol0 + ni * 16 + fr;
        QW[(size_t)gi * 512 + gj] = __float2bfloat16(acc[mi][ni][reg]);
      }
}

// ---------------- EI kernel ----------------
__global__ __launch_bounds__(256) void ei_kernel(const float* __restrict__ ext,
                                                 const float* __restrict__ W1p,
                                                 const float* __restrict__ b1p,
                                                 const float* __restrict__ W2p,
                                                 const float* __restrict__ b2p,
                                                 const float* __restrict__ rbp,
                                                 const int* __restrict__ maskp,
                                                 float* __restrict__ EIF, int ct0) {
  __shared__ float exts[64 * 21];
  __shared__ float W1s[64 * 21];
  __shared__ __hip_bfloat16 Hl[64 * 72];
  const int tid = threadIdx.x;
  const int tblk = blockIdx.x * 64;
  for (int i = tid; i < 64 * 21; i += 256) {
    exts[i] = ext[(size_t)(ct0 + tblk) * 21 + i];
    W1s[i] = W1p[i];
  }
  __syncthreads();
  const int wave = tid >> 6, lane = tid & 63;
#pragma unroll
  for (int k = 0; k < 16; ++k) {
    const int tl = k * 4 + wave;
    float a = b1p[lane];
#pragma unroll
    for (int e = 0; e < 21; ++e) a += exts[tl * 21 + e] * W1s[lane * 21 + e];
    Hl[tl * 72 + lane] = __float2bfloat16(fmaxf(a, 0.f));
  }
  __syncthreads();
  const int fr = lane & 15, kg = lane >> 4;
  const __bf16* Hb = (const __bf16*)Hl;
  bf16x8 a0 = *(const bf16x8*)(Hb + (wave * 16 + fr) * 72 + kg * 8);
  bf16x8 a1 = *(const bf16x8*)(Hb + (wave * 16 + fr) * 72 + 32 + kg * 8);
#pragma unroll
  for (int tile = 0; tile < 9; ++tile) {
    const int o = tile * 16 + fr;
    bf16x8 bv0 = (bf16x8)f2b(0.0f), bv1 = (bf16x8)f2b(0.0f);
    if (o < 136) {
#pragma unroll
      for (int jj = 0; jj < 8; ++jj) {
        bv0[jj] = f2b(W2p[o * 64 + kg * 8 + jj]);
        bv1[jj] = f2b(W2p[o * 64 + 32 + kg * 8 + jj]);
      }
    }
    f32x4 acc = (f32x4)0.0f;
    acc = __builtin_amdgcn_mfma_f32_16x16x32_bf16(a0, bv0, acc, 0, 0, 0);
    acc = __builtin_amdgcn_mfma_f32_16x16x32_bf16(a1, bv1, acc, 0, 0, 0);
    if (o < 136) {
      const int h = (o * 241) >> 12;
      const int r = o - h * 17;
      const float rbo = rbp[o], b2o = b2p[o];
#pragma unroll
      for (int reg = 0; reg < 4; ++reg) {
        const int tl = tblk + wave * 16 + kg * 4 + reg;
        const int m = (ct0 + tl) & (NN - 1);
        float v = maskp[m * NR + r] ? -1e30f : (rbo + 0.01f * (acc[reg] + b2o));
        EIF[(size_t)tl * 136 + o] = v;
      }
    }
  }
}

// ---------------- fused per-token attention: one wave = one token ----------------
__global__ __launch_bounds__(256) void attn_fused(const __hip_bfloat16* __restrict__ pkvB,
                                                  const __hip_bfloat16* __restrict__ qwB,
                                                  const float* __restrict__ eifB,
                                                  __hip_bfloat16* __restrict__ tB) {
  __shared__ __hip_bfloat16 ps[4][16 * 40];
  const int tid = threadIdx.x;
  const int wave = tid >> 6;
  const int lane = tid & 63;
  const int t = blockIdx.x * 4 + wave;
  const __bf16* qw = (const __bf16*)(qwB + (size_t)t * 512);
  const __bf16* pkv = (const __bf16*)(pkvB + (size_t)t * (NR * 64));
  const float* eif = eifB + (size_t)t * 136;
  const int fr = lane & 15;
  const int kg = lane >> 4;

  f32x4 slo = (f32x4)0.0f, shi = (f32x4)0.0f;
#pragma unroll
  for (int kk = 0; kk < 2; ++kk) {
    bf16x8 av = *(const bf16x8*)(qw + fr * 64 + kk * 32 + kg * 8);
    bf16x8 blo = *(const bf16x8*)(pkv + fr * 64 + kk * 32 + kg * 8);
    bf16x8 bhi = (bf16x8)f2b(0.0f);
    if (fr == 0) bhi = *(const bf16x8*)(pkv + 16 * 64 + kk * 32 + kg * 8);
    slo = __builtin_amdgcn_mfma_f32_16x16x32_bf16(av, blo, slo, 0, 0, 0);
    shi = __builtin_amdgcn_mfma_f32_16x16x32_bf16(av, bhi, shi, 0, 0, 0);
  }

  float plo[4], phi[4];
#pragma unroll
  for (int reg = 0; reg < 4; ++reg) {
    const int h = kg * 4 + reg;
    float llo = slo[reg] + eif[h * 17 + fr];
    float lhi = (fr == 0) ? (shi[reg] + eif[h * 17 + 16]) : -1e30f;
    float mx = fmaxf(llo, lhi);
    mx = fmaxf(mx, __shfl_xor(mx, 1));
    mx = fmaxf(mx, __shfl_xor(mx, 2));
    mx = fmaxf(mx, __shfl_xor(mx, 4));
    mx = fmaxf(mx, __shfl_xor(mx, 8));
    float el = __expf(llo - mx);
    float eh = __expf(lhi - mx);
    float sm = el + eh;
    sm += __shfl_xor(sm, 1);
    sm += __shfl_xor(sm, 2);
    sm += __shfl_xor(sm, 4);
    sm += __shfl_xor(sm, 8);
    const float iv = 1.0f / sm;
    plo[reg] = el * iv;
    phi[reg] = eh * iv;
  }

  __hip_bfloat16* pw = ps[wave];
#pragma unroll
  for (int reg = 0; reg < 4; ++reg) {
    const int h = kg * 4 + reg;
    pw[h * 40 + fr] = __float2bfloat16(plo[reg]);
    pw[h * 40 + 16 + fr] = __float2bfloat16(phi[reg]);
  }
  bf16x8 ap = *(const bf16x8*)((const __bf16*)pw + fr * 40 + kg * 8);

#pragma unroll
  for (int ni = 0; ni < 4; ++ni) {
    bf16x8 bv = (bf16x8)f2b(0.0f);
    const __bf16* bsrc = pkv + ni * 16 + fr;
#pragma unroll
    for (int jj = 0; jj < 8; ++jj) {
      const int r = kg * 8 + jj;
      if (r < NR) bv[jj] = bsrc[r * 64];
    }
    f32x4 o = __builtin_amdgcn_mfma_f32_16x16x32_bf16(ap, bv, (f32x4)0.0f, 0, 0, 0);
    if (kg < 2) {
#pragma unroll
      for (int reg = 0; reg < 4; ++reg) {
        const int h = kg * 4 + reg;
        tB[(size_t)t * 512 + h * 64 + ni * 16 + fr] = __float2bfloat16(o[reg]);
      }
    }
  }
}

// ---------------- out GEMM: out[t][j] = T[t][:] @ WVP[j][:] + bp[j], K=512 ----------------
__global__ __launch_bounds__(256) void out_gemm(const __hip_bfloat16* __restrict__ Tb,
                                                const __hip_bfloat16* __restrict__ WVP,
                                                const float* __restrict__ bp,
                                                float* __restrict__ out, int ct0) {
  __shared__ char As[16384];
  __shared__ char Bs[8192];
  const int tid = threadIdx.x;
  const int wave = tid >> 6;
  const int lane = tid & 63;
  const int rowBase = blockIdx.x * 128;
  const int lrow8 = lane >> 3;
  const int gslot = lane & 7;
  const int gsrc = gslot ^ lrow8;
  const int fr = lane & 15;
  const int kg = lane >> 4;

  f32x4 acc[2][4];
#pragma unroll
  for (int i = 0; i < 2; ++i)
#pragma unroll
    for (int j = 0; j < 4; ++j) acc[i][j] = (f32x4)0.0f;

  for (int kt = 0; kt < 8; ++kt) {
#pragma unroll
    for (int cc = 0; cc < 4; ++cc) {
      const int r0 = wave * 32 + cc * 8;
      gload_lds16(Tb + ((size_t)(rowBase + r0 + lrow8) * 512 + kt * 64 + gsrc * 8),
                  As + r0 * 128);
    }
#pragma unroll
    for (int cc = 0; cc < 2; ++cc) {
      const int r0 = cc * 32 + wave * 8;
      gload_lds16(WVP + ((size_t)(r0 + lrow8) * 512 + kt * 64 + gsrc * 8), Bs + r0 * 128);
    }
    __syncthreads();
#pragma unroll
    for (int kk = 0; kk < 2; ++kk) {
      bf16x8 av[2], bv[4];
#pragma unroll
      for (int mi = 0; mi < 2; ++mi) {
        const int row = wave * 32 + mi * 16 + fr;
        const int slot = (kk * 4 + kg) ^ (row & 7);
        av[mi] = *(const bf16x8*)(As + row * 128 + slot * 16);
      }
#pragma unroll
      for (int ni = 0; ni < 4; ++ni) {
        const int row = ni * 16 + fr;
        const int slot = (kk * 4 + kg) ^ (row & 7);
        bv[ni] = *(const bf16x8*)(Bs + row * 128 + slot * 16);
      }
#pragma unroll
      for (int mi = 0; mi < 2; ++mi)
#pragma unroll
        for (int ni = 0; ni < 4; ++ni)
          acc[mi][ni] =
              __builtin_amdgcn_mfma_f32_16x16x32_bf16(av[mi], bv[ni], acc[mi][ni], 0, 0, 0);
    }
    __syncthreads();
  }

  const int rq = lane >> 4;
#pragma unroll
  for (int mi = 0; mi < 2; ++mi)
#pragma unroll
    for (int ni = 0; ni < 4; ++ni) {
      const int gj = ni * 16 + fr;
      const float bpv = bp[gj];
#pragma unroll
      for (int reg = 0; reg < 4; ++reg) {
        const int gi = rowBase + wave * 32 + mi * 16 + rq * 4 + reg;
        out[(size_t)(ct0 + gi) * 64 + gj] = acc[mi][ni][reg] + bpv;
      }
    }
}

extern "C" void kernel_launch(void* const* d_in, const int* in_sizes, int n_in, void* d_out,
                              int out_size, void* d_ws, size_t ws_size, hipStream_t stream) {
  const float* x = (const float*)d_in[0];
  const float* ext = (const float*)d_in[1];
  const float* assign = (const float*)d_in[2];
  const float* Wq = (const float*)d_in[3];
  const float* Wkv = (const float*)d_in[4];
  const float* rb = (const float*)d_in[5];
  const float* W1 = (const float*)d_in[6];
  const float* b1 = (const float*)d_in[7];
  const float* W2 = (const float*)d_in[8];
  const float* b2 = (const float*)d_in[9];
  const float* Wp = (const float*)d_in[10];
  const float* bp = (const float*)d_in[11];
  const int* mask = (const int*)d_in[12];
  float* out = (float*)d_out;

  char* ws = (char*)d_ws;
  const size_t szA2 = 8912896;
  const size_t szWQK = 65536;
  const size_t szWVP = 65536;
  const size_t fixed = szA2 + szWQK + szWVP;

  int nchunks = 4;
  {
    const int cand[3] = {1, 2, 4};
    for (int ci = 0; ci < 3; ++ci) {
      const size_t ntk = 32768 / cand[ci];
      const size_t nbb = 64 / cand[ci];
      const size_t need = fixed + nbb * 65536 + ntk * 128 + ntk * 2176 +
                          (ntk * 1024 + 2048) + (ntk * 544 + 4096) + ntk * 1024;
      if (need <= ws_size) { nchunks = cand[ci]; break; }
    }
  }
  const int ntok = 32768 / nchunks;
  const int nb = 64 / nchunks;

  __hip_bfloat16* A2 = (__hip_bfloat16*)(ws);
  __hip_bfloat16* WQK = (__hip_bfloat16*)(ws + szA2);
  __hip_bfloat16* WVP = (__hip_bfloat16*)(ws + szA2 + szWQK);
  char* p = ws + fixed;
  __hip_bfloat16* XT = (__hip_bfloat16*)p;
  p += (size_t)nb * 65536;
  __hip_bfloat16* XR = (__hip_bfloat16*)p;
  p += (size_t)ntok * 128;
  __hip_bfloat16* PKV = (__hip_bfloat16*)p;
  p += (size_t)ntok * 2176;
  __hip_bfloat16* QW = (__hip_bfloat16*)p;
  p += (size_t)ntok * 1024 + 2048;
  float* EIF = (float*)p;
  p += (size_t)ntok * 544 + 4096;
  __hip_bfloat16* TBUF = (__hip_bfloat16*)p;

  hipLaunchKernelGGL(pack_A, dim3(4, 512), dim3(256), 0, stream, assign, A2);
  hipLaunchKernelGGL(prep_w, dim3(64), dim3(256), 0, stream, Wq, Wkv, Wp, WQK, WVP);

  for (int ck = 0; ck < nchunks; ++ck) {
    const int b0 = ck * nb;
    const int ct0 = ck * ntok;
    hipLaunchKernelGGL(pack_X, dim3(4, nb), dim3(256), 0, stream, x, XT, XR, b0);
    hipLaunchKernelGGL(gemm_prekv, dim3(nb / 2, 68), dim3(256), 0, stream, A2, XT, PKV);
    hipLaunchKernelGGL(qw_gemm, dim3(4, ntok / 128), dim3(256), 0, stream, XR, WQK, QW);
    hipLaunchKernelGGL(ei_kernel, dim3(ntok / 64), dim3(256), 0, stream, ext, W1, b1, W2, b2,
                       rb, mask, EIF, ct0);
    hipLaunchKernelGGL(attn_fused, dim3(ntok / 4), dim3(256), 0, stream, PKV, QW, EIF, TBUF);
    hipLaunchKernelGGL(out_gemm, dim3(ntok / 128), dim3(256), 0, stream, TBUF, WVP, bp, out,
                       ct0);
  }
}

// Round 4
// 266.461 us; speedup vs baseline: 1.8184x; 1.0104x over previous
//
#include <hip/hip_runtime.h>
#include <hip/hip_bf16.h>

typedef __bf16 bf16x8 __attribute__((ext_vector_type(8)));
typedef float f32x4 __attribute__((ext_vector_type(4)));

#define NN 512
#define NR 17

// swizzle a byte offset within a 1024-B row: XOR 16B-granule index with (row&7)
#define SWZ(row, b) (((((b) >> 4) ^ ((row) & 7)) << 4) | ((b) & 15))

__device__ __forceinline__ __bf16 f2b(float f) {
  __hip_bfloat16 h = __float2bfloat16(f);
  return __builtin_bit_cast(__bf16, h);
}

__device__ __forceinline__ void gload_lds16(const void* g, void* l) {
  __builtin_amdgcn_global_load_lds(
      (const __attribute__((address_space(1))) void*)g,
      (__attribute__((address_space(3))) void*)l, 16, 0, 0);
}

// ---------------- pack assignment [m][n][r] -> A2 [(m*17+r)][n] bf16 ----------------
__global__ __launch_bounds__(256) void pack_A(const float* __restrict__ a,
                                              __hip_bfloat16* __restrict__ A2) {
  __shared__ __hip_bfloat16 T[NR * 136];
  const int m = blockIdx.y;
  const int n0 = blockIdx.x * 128;
  const float* src = a + (size_t)m * (NN * NR) + (size_t)n0 * NR;
  for (int t = threadIdx.x; t < 128 * NR; t += 256) {
    int i = t / NR;
    int r = t - i * NR;
    T[r * 136 + i] = __float2bfloat16(src[t]);
  }
  __syncthreads();
  for (int t = threadIdx.x; t < NR * 128; t += 256) {
    int r = t >> 7;
    int i = t & 127;
    A2[((size_t)m * NR + r) * NN + n0 + i] = T[r * 136 + i];
  }
}

// ---------------- pack x: XT [(b*64+c)][n] bf16 + XR [t][c] bf16 ----------------
__global__ __launch_bounds__(256) void pack_X(const float* __restrict__ x,
                                              __hip_bfloat16* __restrict__ XT,
                                              __hip_bfloat16* __restrict__ XR) {
  __shared__ __hip_bfloat16 T[64 * 136];
  const int by = blockIdx.y;
  const int n0 = blockIdx.x * 128;
  const float* src = x + ((size_t)by * NN + n0) * 64;
  for (int t = threadIdx.x; t < 128 * 64; t += 256) {
    int i = t >> 6;
    int c = t & 63;
    __hip_bfloat16 v = __float2bfloat16(src[t]);
    T[c * 136 + i] = v;
    XR[((size_t)by * NN + n0 + i) * 64 + c] = v;
  }
  __syncthreads();
  for (int t = threadIdx.x; t < 64 * 128; t += 256) {
    int c = t >> 7;
    int i = t & 127;
    XT[((size_t)by * 64 + c) * NN + n0 + i] = T[c * 136 + i];
  }
}

// ---------------- prep combined weights ----------------
__global__ __launch_bounds__(256) void prep_w(const float* __restrict__ Wq,
                                              const float* __restrict__ Wkv,
                                              const float* __restrict__ Wp,
                                              __hip_bfloat16* __restrict__ WQK,
                                              __hip_bfloat16* __restrict__ WVP) {
  const int base = blockIdx.x * 512 + threadIdx.x;
#pragma unroll
  for (int k = 0; k < 2; ++k) {
    const int idx = base + k * 256;
    {
      const int i = idx & 63, row = idx >> 6, h = row >> 6, c = row & 63;
      float a = 0.f;
#pragma unroll
      for (int d = 0; d < 8; ++d) a += Wq[(h * 8 + d) * 64 + i] * Wkv[(h * 8 + d) * 64 + c];
      WQK[idx] = __float2bfloat16(a * 0.35355339059327373f);
    }
    {
      const int hc = idx & 511, j = idx >> 9, h = hc >> 6, c = hc & 63;
      float a = 0.f;
#pragma unroll
      for (int d = 0; d < 8; ++d)
        a += Wkv[4096 + (h * 8 + d) * 64 + c] * Wp[j * 64 + (h * 8 + d)];
      WVP[idx] = __float2bfloat16(a);
    }
  }
}

// ---------------- pre_kv GEMM (XCD-swizzled) ----------------
#define PREKV_NWG 2176 /* 32 x 68 */
__global__ __launch_bounds__(256) void gemm_prekv(const __hip_bfloat16* __restrict__ A2,
                                                  const __hip_bfloat16* __restrict__ XT,
                                                  __hip_bfloat16* __restrict__ pkv) {
  __shared__ char As[16384];
  __shared__ char Bs[16384];
  const int tid = threadIdx.x;
  const int wave = tid >> 6;
  const int lane = tid & 63;
  // bijective XCD swizzle (2176 % 8 == 0)
  const int flat = blockIdx.y * gridDim.x + blockIdx.x;
  const int s = (flat & 7) * (PREKV_NWG / 8) + (flat >> 3);
  const int rowBase = (s >> 5) * 128;
  const int colBase = (s & 31) * 128;
  const int wrow0 = (wave >> 1) * 64;
  const int wcol0 = (wave & 1) * 64;
  const int lrow8 = lane >> 3;
  const int gslot = lane & 7;
  const int gsrc = gslot ^ lrow8;

  f32x4 acc[4][4];
#pragma unroll
  for (int i = 0; i < 4; ++i)
#pragma unroll
    for (int j = 0; j < 4; ++j) acc[i][j] = (f32x4)0.0f;

  const int fr = lane & 15;
  const int kg = lane >> 4;

  for (int kt = 0; kt < NN; kt += 64) {
#pragma unroll
    for (int cc = 0; cc < 4; ++cc) {
      const int r0 = wave * 32 + cc * 8;
      gload_lds16(A2 + ((size_t)(rowBase + r0 + lrow8) * NN + kt + gsrc * 8), As + r0 * 128);
      gload_lds16(XT + ((size_t)(colBase + r0 + lrow8) * NN + kt + gsrc * 8), Bs + r0 * 128);
    }
    __syncthreads();
#pragma unroll
    for (int kk = 0; kk < 2; ++kk) {
      bf16x8 av[4], bv[4];
#pragma unroll
      for (int mi = 0; mi < 4; ++mi) {
        const int row = wrow0 + mi * 16 + fr;
        const int slot = (kk * 4 + kg) ^ (row & 7);
        av[mi] = *(const bf16x8*)(As + row * 128 + slot * 16);
      }
#pragma unroll
      for (int ni = 0; ni < 4; ++ni) {
        const int row = wcol0 + ni * 16 + fr;
        const int slot = (kk * 4 + kg) ^ (row & 7);
        bv[ni] = *(const bf16x8*)(Bs + row * 128 + slot * 16);
      }
#pragma unroll
      for (int mi = 0; mi < 4; ++mi)
#pragma unroll
        for (int ni = 0; ni < 4; ++ni)
          acc[mi][ni] =
              __builtin_amdgcn_mfma_f32_16x16x32_bf16(av[mi], bv[ni], acc[mi][ni], 0, 0, 0);
    }
    __syncthreads();
  }

  const int rq = lane >> 4;
#pragma unroll
  for (int mi = 0; mi < 4; ++mi) {
#pragma unroll
    for (int ni = 0; ni < 4; ++ni) {
#pragma unroll
      for (int reg = 0; reg < 4; ++reg) {
        const int gi = rowBase + wrow0 + mi * 16 + rq * 4 + reg;
        const int gj = colBase + wcol0 + ni * 16 + fr;
        const unsigned m = (unsigned)gi / 17u;
        const unsigned r = (unsigned)gi - m * 17u;
        const int bb = gj >> 6;
        const int c = gj & 63;
        pkv[(((size_t)bb * NN + m) * NR + r) * 64 + c] = __float2bfloat16(acc[mi][ni][reg]);
      }
    }
  }
}

// ---------------- EI kernel: EIF[t][o] = mask ? -1e30 : rb + 0.01*(MLP(ext)) ----------------
__global__ __launch_bounds__(256) void ei_kernel(const float* __restrict__ ext,
                                                 const float* __restrict__ W1p,
                                                 const float* __restrict__ b1p,
                                                 const float* __restrict__ W2p,
                                                 const float* __restrict__ b2p,
                                                 const float* __restrict__ rbp,
                                                 const int* __restrict__ maskp,
                                                 float* __restrict__ EIF) {
  __shared__ float exts[64 * 21];
  __shared__ float W1s[64 * 21];
  __shared__ __hip_bfloat16 Hl[64 * 72];
  const int tid = threadIdx.x;
  const int tblk = blockIdx.x * 64;
  for (int i = tid; i < 64 * 21; i += 256) {
    exts[i] = ext[(size_t)tblk * 21 + i];
    W1s[i] = W1p[i];
  }
  __syncthreads();
  const int wave = tid >> 6, lane = tid & 63;
#pragma unroll
  for (int k = 0; k < 16; ++k) {
    const int tl = k * 4 + wave;
    float a = b1p[lane];
#pragma unroll
    for (int e = 0; e < 21; ++e) a += exts[tl * 21 + e] * W1s[lane * 21 + e];
    Hl[tl * 72 + lane] = __float2bfloat16(fmaxf(a, 0.f));
  }
  __syncthreads();
  const int fr = lane & 15, kg = lane >> 4;
  const __bf16* Hb = (const __bf16*)Hl;
  bf16x8 a0 = *(const bf16x8*)(Hb + (wave * 16 + fr) * 72 + kg * 8);
  bf16x8 a1 = *(const bf16x8*)(Hb + (wave * 16 + fr) * 72 + 32 + kg * 8);
#pragma unroll
  for (int tile = 0; tile < 9; ++tile) {
    const int o = tile * 16 + fr;
    bf16x8 bv0 = (bf16x8)f2b(0.0f), bv1 = (bf16x8)f2b(0.0f);
    if (o < 136) {
#pragma unroll
      for (int jj = 0; jj < 8; ++jj) {
        bv0[jj] = f2b(W2p[o * 64 + kg * 8 + jj]);
        bv1[jj] = f2b(W2p[o * 64 + 32 + kg * 8 + jj]);
      }
    }
    f32x4 acc = (f32x4)0.0f;
    acc = __builtin_amdgcn_mfma_f32_16x16x32_bf16(a0, bv0, acc, 0, 0, 0);
    acc = __builtin_amdgcn_mfma_f32_16x16x32_bf16(a1, bv1, acc, 0, 0, 0);
    if (o < 136) {
      const int h = (o * 241) >> 12;
      const int r = o - h * 17;
      const float rbo = rbp[o], b2o = b2p[o];
#pragma unroll
      for (int reg = 0; reg < 4; ++reg) {
        const int tl = tblk + wave * 16 + kg * 4 + reg;
        const int m = tl & (NN - 1);
        float v = maskp[m * NR + r] ? -1e30f : (rbo + 0.01f * (acc[reg] + b2o));
        EIF[(size_t)tl * 136 + o] = v;
      }
    }
  }
}

// ---------------- mega-fused attention: qw + QK + softmax + PV + out-proj ----------------
// block = 32 tokens, 4 waves. LDS: qw_s[32][1024B] + T_s[32][1024B] + pkvT[4][4KB] = 80 KiB
__global__ __launch_bounds__(256, 2) void attn_mega(
    const __hip_bfloat16* __restrict__ XRp, const __hip_bfloat16* __restrict__ WQKp,
    const __hip_bfloat16* __restrict__ WVPp, const __hip_bfloat16* __restrict__ pkvB,
    const float* __restrict__ eifB, const float* __restrict__ bpp,
    float* __restrict__ outp) {
  extern __shared__ char smem[];
  char* qws = smem;           // [32] rows of 1024 B, granule-swizzled
  char* Ts = smem + 32768;    // [32] rows of 1024 B, granule-swizzled (ps scratch + T)
  const int tid = threadIdx.x;
  const int wave = tid >> 6;
  const int lane = tid & 63;
  const int fr = lane & 15;
  const int kg = lane >> 4;  // also D-row quadrant
  const int t0 = blockIdx.x * 32;
  char* pT = smem + 65536 + wave * 4096;  // [64 c][64 B], granule-swizzled

  // ---- P0: qw_s = XR(tokens) @ WQK^T  (M=32, N=512, K=64) ----
  {
    const int rt = wave >> 1;
    const int ct0 = (wave & 1) * 16;
    bf16x8 a0 = *(const bf16x8*)((const __bf16*)XRp + (size_t)(t0 + rt * 16 + fr) * 64 + kg * 8);
    bf16x8 a1 =
        *(const bf16x8*)((const __bf16*)XRp + (size_t)(t0 + rt * 16 + fr) * 64 + 32 + kg * 8);
#pragma unroll
    for (int ci = 0; ci < 16; ++ci) {
      const int ct = ct0 + ci;
      f32x4 acc = (f32x4)0.0f;
      bf16x8 b0 = *(const bf16x8*)((const __bf16*)WQKp + (size_t)(ct * 16 + fr) * 64 + kg * 8);
      bf16x8 b1 =
          *(const bf16x8*)((const __bf16*)WQKp + (size_t)(ct * 16 + fr) * 64 + 32 + kg * 8);
      acc = __builtin_amdgcn_mfma_f32_16x16x32_bf16(a0, b0, acc, 0, 0, 0);
      acc = __builtin_amdgcn_mfma_f32_16x16x32_bf16(a1, b1, acc, 0, 0, 0);
#pragma unroll
      for (int reg = 0; reg < 4; ++reg) {
        const int row = rt * 16 + kg * 4 + reg;
        const int col = ct * 16 + fr;
        *(__hip_bfloat16*)(qws + row * 1024 + SWZ(row, col * 2)) = __float2bfloat16(acc[reg]);
      }
    }
  }

  // ---- zero pT ONCE per wave (r=17..31 slots must be 0.0 bf16, NOT uninit LDS:
  //      PV's MFMA sums 0*B over k=17..31 and 0*Inf/NaN garbage = NaN) ----
  {
    bf16x8 z = (bf16x8)f2b(0.0f);
#pragma unroll
    for (int j = 0; j < 4; ++j) *(bf16x8*)(pT + lane * 64 + j * 16) = z;
  }
  __syncthreads();

  // ---- P1: per-wave token loop (8 tokens each) ----
  for (int i = 0; i < 8; ++i) {
    const int tl = wave * 8 + i;
    const size_t tg = (size_t)t0 + tl;
    const __bf16* pk = (const __bf16*)pkvB + tg * 1088;

    // stage pkv^T into pT: [c][r] with 16B-granule slot = (r>>3) ^ ((c>>2)&3)
    bf16x8 v0 = *(const bf16x8*)(pk + lane * 8);
    bf16x8 v1 = *(const bf16x8*)(pk + 512 + lane * 8);
    __bf16 vt = pk[1024 + lane];
    {
      const int r0 = lane >> 3;  // v0 row; v1 row = r0+8 (same &7)
      const int cb = (lane & 7) * 8;
#pragma unroll
      for (int j = 0; j < 8; ++j) {
        const int c = cb + j;
        const int sl0 = (0 ^ ((c >> 2) & 3)) << 4;
        const int sl1 = (1 ^ ((c >> 2) & 3)) << 4;
        *(__bf16*)(pT + c * 64 + sl0 + r0 * 2) = v0[j];
        *(__bf16*)(pT + c * 64 + sl1 + r0 * 2) = v1[j];
      }
      const int c = lane;
      *(__bf16*)(pT + c * 64 + ((2 ^ ((c >> 2) & 3)) << 4)) = vt;  // r=16
    }

    // QK: S[h][r] via 2 kk x (lo,hi)
    f32x4 slo = (f32x4)0.0f, shi = (f32x4)0.0f;
#pragma unroll
    for (int kk = 0; kk < 2; ++kk) {
      const int g = fr * 8 + kk * 4 + kg;
      bf16x8 av = *(const bf16x8*)(qws + tl * 1024 + ((g ^ (tl & 7)) << 4));
      bf16x8 blo = *(const bf16x8*)(pk + fr * 64 + kk * 32 + kg * 8);
      bf16x8 bhi = (bf16x8)f2b(0.0f);
      if (fr == 0) bhi = *(const bf16x8*)(pk + 1024 + kk * 32 + kg * 8);
      slo = __builtin_amdgcn_mfma_f32_16x16x32_bf16(av, blo, slo, 0, 0, 0);
      shi = __builtin_amdgcn_mfma_f32_16x16x32_bf16(av, bhi, shi, 0, 0, 0);
    }

    // softmax (per h = kg*4+reg over r = fr lanes + r16)
    const float* eif = eifB + tg * 136;
    float plo[4], phi[4];
#pragma unroll
    for (int reg = 0; reg < 4; ++reg) {
      const int h = kg * 4 + reg;
      float llo = slo[reg] + eif[h * 17 + fr];
      float lhi = (fr == 0) ? (shi[reg] + eif[h * 17 + 16]) : -1e30f;
      float mx = fmaxf(llo, lhi);
      mx = fmaxf(mx, __shfl_xor(mx, 1));
      mx = fmaxf(mx, __shfl_xor(mx, 2));
      mx = fmaxf(mx, __shfl_xor(mx, 4));
      mx = fmaxf(mx, __shfl_xor(mx, 8));
      float el = __expf(llo - mx);
      float eh = __expf(lhi - mx);
      float sm = el + eh;
      sm += __shfl_xor(sm, 1);
      sm += __shfl_xor(sm, 2);
      sm += __shfl_xor(sm, 4);
      sm += __shfl_xor(sm, 8);
      const float iv = 1.0f / sm;
      plo[reg] = el * iv;
      phi[reg] = eh * iv;  // 0 for fr!=0 naturally
    }

    // P -> Ts row tl as [h][32] scratch (r pad 17..31 covered by phi zeros)
#pragma unroll
    for (int reg = 0; reg < 4; ++reg) {
      const int h = kg * 4 + reg;
      *(__hip_bfloat16*)(Ts + tl * 1024 + SWZ(tl, (h * 32 + fr) * 2)) =
          __float2bfloat16(plo[reg]);
      *(__hip_bfloat16*)(Ts + tl * 1024 + SWZ(tl, (h * 32 + 16 + fr) * 2)) =
          __float2bfloat16(phi[reg]);
    }
    bf16x8 ap = *(const bf16x8*)(Ts + tl * 1024 + (((fr * 4 + kg) ^ (tl & 7)) << 4));

    // PV: T[h][c] = sum_r P[h][r] * pkvT[c][r]; overwrite Ts row with T[h*64+c]
#pragma unroll
    for (int ni = 0; ni < 4; ++ni) {
      const int c = ni * 16 + fr;
      bf16x8 bv = *(const bf16x8*)(pT + c * 64 + ((kg ^ ((c >> 2) & 3)) << 4));
      f32x4 o = __builtin_amdgcn_mfma_f32_16x16x32_bf16(ap, bv, (f32x4)0.0f, 0, 0, 0);
      if (kg < 2) {
#pragma unroll
        for (int reg = 0; reg < 4; ++reg) {
          const int h = kg * 4 + reg;
          *(__hip_bfloat16*)(Ts + tl * 1024 + SWZ(tl, (h * 64 + c) * 2)) =
              __float2bfloat16(o[reg]);
        }
      }
    }
  }
  __syncthreads();

  // ---- P2: out = T_s @ WVP^T + bp  (M=32, N=64, K=512) ----
  {
    const int rt = wave >> 1;
    const int ct_base = (wave & 1) * 2;
#pragma unroll
    for (int cj = 0; cj < 2; ++cj) {
      const int ct = ct_base + cj;
      f32x4 acc = (f32x4)0.0f;
#pragma unroll
      for (int kk = 0; kk < 16; ++kk) {
        const int row = rt * 16 + fr;
        bf16x8 a = *(const bf16x8*)(Ts + row * 1024 + (((kk * 4 + kg) ^ (row & 7)) << 4));
        bf16x8 b = *(const bf16x8*)((const __bf16*)WVPp + (size_t)(ct * 16 + fr) * 512 +
                                    kk * 32 + kg * 8);
        acc = __builtin_amdgcn_mfma_f32_16x16x32_bf16(a, b, acc, 0, 0, 0);
      }
      const float bpv = bpp[ct * 16 + fr];
#pragma unroll
      for (int reg = 0; reg < 4; ++reg)
        outp[(size_t)(t0 + rt * 16 + kg * 4 + reg) * 64 + ct * 16 + fr] = acc[reg] + bpv;
    }
  }
}

extern "C" void kernel_launch(void* const* d_in, const int* in_sizes, int n_in, void* d_out,
                              int out_size, void* d_ws, size_t ws_size, hipStream_t stream) {
  const float* x = (const float*)d_in[0];
  const float* ext = (const float*)d_in[1];
  const float* assign = (const float*)d_in[2];
  const float* Wq = (const float*)d_in[3];
  const float* Wkv = (const float*)d_in[4];
  const float* rb = (const float*)d_in[5];
  const float* W1 = (const float*)d_in[6];
  const float* b1 = (const float*)d_in[7];
  const float* W2 = (const float*)d_in[8];
  const float* b2 = (const float*)d_in[9];
  const float* Wp = (const float*)d_in[10];
  const float* bp = (const float*)d_in[11];
  const int* mask = (const int*)d_in[12];
  float* out = (float*)d_out;

  char* ws = (char*)d_ws;
  __hip_bfloat16* A2 = (__hip_bfloat16*)(ws + 0);           // 8,912,896
  __hip_bfloat16* WQK = (__hip_bfloat16*)(ws + 8912896);    // 65,536
  __hip_bfloat16* WVP = (__hip_bfloat16*)(ws + 8978432);    // 65,536
  __hip_bfloat16* XT = (__hip_bfloat16*)(ws + 9043968);     // 4,194,304
  __hip_bfloat16* XR = (__hip_bfloat16*)(ws + 13238272);    // 4,194,304
  __hip_bfloat16* PKV = (__hip_bfloat16*)(ws + 17432576);   // 71,303,168
  float* EIF = (float*)(ws + 88735744);                     // 17,825,792 + 4096 pad
  if (ws_size < (size_t)106565632) return;

  hipLaunchKernelGGL(pack_A, dim3(4, 512), dim3(256), 0, stream, assign, A2);
  hipLaunchKernelGGL(prep_w, dim3(64), dim3(256), 0, stream, Wq, Wkv, Wp, WQK, WVP);
  hipLaunchKernelGGL(pack_X, dim3(4, 64), dim3(256), 0, stream, x, XT, XR);
  hipLaunchKernelGGL(gemm_prekv, dim3(32, 68), dim3(256), 0, stream, A2, XT, PKV);
  hipLaunchKernelGGL(ei_kernel, dim3(512), dim3(256), 0, stream, ext, W1, b1, W2, b2, rb, mask,
                     EIF);
  hipFuncSetAttribute((const void*)attn_mega, hipFuncAttributeMaxDynamicSharedMemorySize, 81920);
  hipLaunchKernelGGL(attn_mega, dim3(1024), dim3(256), 81920, stream, XR, WQK, WVP, PKV, EIF, bp,
                     out);
}

// Round 8
// 228.571 us; speedup vs baseline: 2.1199x; 1.1658x over previous
//
#include <hip/hip_runtime.h>
#include <hip/hip_bf16.h>

typedef __bf16 bf16x8 __attribute__((ext_vector_type(8)));
typedef float f32x4 __attribute__((ext_vector_type(4)));

#define NN 512
#define NR 17

// swizzle a byte offset within a 1024-B row: XOR 16B-granule index with (row&7)
#define SWZ(row, b) (((((b) >> 4) ^ ((row) & 7)) << 4) | ((b) & 15))

__device__ __forceinline__ float bf2f(__hip_bfloat16 v) { return __bfloat162float(v); }
__device__ __forceinline__ __bf16 f2b(float f) {
  __hip_bfloat16 h = __float2bfloat16(f);
  return __builtin_bit_cast(__bf16, h);
}
__device__ __forceinline__ unsigned pkbf(float a, float b) {
  unsigned ua = (unsigned)__builtin_bit_cast(unsigned short, __float2bfloat16(a));
  unsigned ub = (unsigned)__builtin_bit_cast(unsigned short, __float2bfloat16(b));
  return ua | (ub << 16);
}

__device__ __forceinline__ void gload_lds16(const void* g, void* l) {
  __builtin_amdgcn_global_load_lds(
      (const __attribute__((address_space(1))) void*)g,
      (__attribute__((address_space(3))) void*)l, 16, 0, 0);
}

// ---------------- pack assignment [m][n][r] -> A2 [(m*17+r)][n] bf16 ----------------
__global__ __launch_bounds__(256) void pack_A(const float* __restrict__ a,
                                              __hip_bfloat16* __restrict__ A2) {
  __shared__ __hip_bfloat16 T[NR * 136];
  const int m = blockIdx.y;
  const int n0 = blockIdx.x * 128;
  const float* src = a + (size_t)m * (NN * NR) + (size_t)n0 * NR;
  for (int t = threadIdx.x; t < 128 * NR; t += 256) {
    int i = t / NR;
    int r = t - i * NR;
    T[r * 136 + i] = __float2bfloat16(src[t]);
  }
  __syncthreads();
  for (int t = threadIdx.x; t < NR * 128; t += 256) {
    int r = t >> 7;
    int i = t & 127;
    A2[((size_t)m * NR + r) * NN + n0 + i] = T[r * 136 + i];
  }
}

// ---------------- pack x: XT [(b*64+c)][n] bf16 + XR [t][c] bf16 ----------------
__global__ __launch_bounds__(256) void pack_X(const float* __restrict__ x,
                                              __hip_bfloat16* __restrict__ XT,
                                              __hip_bfloat16* __restrict__ XR) {
  __shared__ __hip_bfloat16 T[64 * 136];
  const int by = blockIdx.y;
  const int n0 = blockIdx.x * 128;
  const float* src = x + ((size_t)by * NN + n0) * 64;
  for (int t = threadIdx.x; t < 128 * 64; t += 256) {
    int i = t >> 6;
    int c = t & 63;
    __hip_bfloat16 v = __float2bfloat16(src[t]);
    T[c * 136 + i] = v;
    XR[((size_t)by * NN + n0 + i) * 64 + c] = v;
  }
  __syncthreads();
  for (int t = threadIdx.x; t < 64 * 128; t += 256) {
    int c = t >> 7;
    int i = t & 127;
    XT[((size_t)by * 64 + c) * NN + n0 + i] = T[c * 136 + i];
  }
}

// ---------------- prep combined weights ----------------
__global__ __launch_bounds__(256) void prep_w(const float* __restrict__ Wq,
                                              const float* __restrict__ Wkv,
                                              const float* __restrict__ Wp,
                                              __hip_bfloat16* __restrict__ WQK,
                                              __hip_bfloat16* __restrict__ WVP) {
  const int base = blockIdx.x * 512 + threadIdx.x;
#pragma unroll
  for (int k = 0; k < 2; ++k) {
    const int idx = base + k * 256;
    {
      const int i = idx & 63, row = idx >> 6, h = row >> 6, c = row & 63;
      float a = 0.f;
#pragma unroll
      for (int d = 0; d < 8; ++d) a += Wq[(h * 8 + d) * 64 + i] * Wkv[(h * 8 + d) * 64 + c];
      WQK[idx] = __float2bfloat16(a * 0.35355339059327373f);
    }
    {
      const int hc = idx & 511, j = idx >> 9, h = hc >> 6, c = hc & 63;
      float a = 0.f;
#pragma unroll
      for (int d = 0; d < 8; ++d)
        a += Wkv[4096 + (h * 8 + d) * 64 + c] * Wp[j * 64 + (h * 8 + d)];
      WVP[idx] = __float2bfloat16(a);
    }
  }
}

// ---------------- mask scan: compacted list of live (m,r) rows ----------------
__global__ __launch_bounds__(512) void mask_scan(const int* __restrict__ maskp,
                                                 int* __restrict__ rowsp,
                                                 int* __restrict__ metap) {
  __shared__ int sc[512];
  const int tid = threadIdx.x;
  int c = 0;
#pragma unroll
  for (int r = 0; r < NR; ++r) c += (maskp[tid * NR + r] == 0) ? 1 : 0;
  sc[tid] = c;
  __syncthreads();
  for (int s = 1; s < 512; s <<= 1) {
    int v = (tid >= s) ? sc[tid - s] : 0;
    __syncthreads();
    sc[tid] += v;
    __syncthreads();
  }
  int idx = sc[tid] - c;  // exclusive prefix
#pragma unroll
  for (int r = 0; r < NR; ++r)
    if (maskp[tid * NR + r] == 0) rowsp[idx++] = tid * NR + r;
  if (tid == 511) {
    const int total = sc[511];
    const int padded = (total + 127) & ~127;
    for (int i = total; i < padded; ++i) rowsp[i] = 0;  // benign duplicates
    metap[0] = padded;
  }
}

// ---------------- pre_kv GEMM over compacted rows ----------------
__global__ __launch_bounds__(256) void gemm_prekv(const __hip_bfloat16* __restrict__ A2,
                                                  const __hip_bfloat16* __restrict__ XT,
                                                  const int* __restrict__ rowsp,
                                                  const int* __restrict__ metap,
                                                  __hip_bfloat16* __restrict__ pkv) {
  __shared__ char As[16384];
  __shared__ char Bs[16384];
  const int padded = metap[0];
  const int nwg = (padded >> 7) * 32;  // active blocks (multiple of 8)
  const int flat = blockIdx.y * gridDim.x + blockIdx.x;
  if (flat >= nwg) return;
  const int s = (flat & 7) * (nwg >> 3) + (flat >> 3);  // bijective XCD swizzle
  const int rowBase = (s >> 5) * 128;
  const int colBase = (s & 31) * 128;

  const int tid = threadIdx.x;
  const int wave = tid >> 6;
  const int lane = tid & 63;
  const int wrow0 = (wave >> 1) * 64;
  const int wcol0 = (wave & 1) * 64;
  const int lrow8 = lane >> 3;
  const int gslot = lane & 7;
  const int gsrc = gslot ^ lrow8;

  int arow[4];
#pragma unroll
  for (int cc = 0; cc < 4; ++cc)
    arow[cc] = rowsp[rowBase + wave * 32 + cc * 8 + lrow8];

  f32x4 acc[4][4];
#pragma unroll
  for (int i = 0; i < 4; ++i)
#pragma unroll
    for (int j = 0; j < 4; ++j) acc[i][j] = (f32x4)0.0f;

  const int fr = lane & 15;
  const int kg = lane >> 4;

  for (int kt = 0; kt < NN; kt += 64) {
#pragma unroll
    for (int cc = 0; cc < 4; ++cc) {
      const int r0 = wave * 32 + cc * 8;
      gload_lds16(A2 + ((size_t)arow[cc] * NN + kt + gsrc * 8), As + r0 * 128);
      gload_lds16(XT + ((size_t)(colBase + r0 + lrow8) * NN + kt + gsrc * 8), Bs + r0 * 128);
    }
    __syncthreads();
#pragma unroll
    for (int kk = 0; kk < 2; ++kk) {
      bf16x8 av[4], bv[4];
#pragma unroll
      for (int mi = 0; mi < 4; ++mi) {
        const int row = wrow0 + mi * 16 + fr;
        const int slot = (kk * 4 + kg) ^ (row & 7);
        av[mi] = *(const bf16x8*)(As + row * 128 + slot * 16);
      }
#pragma unroll
      for (int ni = 0; ni < 4; ++ni) {
        const int row = wcol0 + ni * 16 + fr;
        const int slot = (kk * 4 + kg) ^ (row & 7);
        bv[ni] = *(const bf16x8*)(Bs + row * 128 + slot * 16);
      }
#pragma unroll
      for (int mi = 0; mi < 4; ++mi)
#pragma unroll
        for (int ni = 0; ni < 4; ++ni)
          acc[mi][ni] =
              __builtin_amdgcn_mfma_f32_16x16x32_bf16(av[mi], bv[ni], acc[mi][ni], 0, 0, 0);
    }
    __syncthreads();
  }

  const int rq = lane >> 4;
#pragma unroll
  for (int mi = 0; mi < 4; ++mi) {
#pragma unroll
    for (int ni = 0; ni < 4; ++ni) {
#pragma unroll
      for (int reg = 0; reg < 4; ++reg) {
        const int gi = rowBase + wrow0 + mi * 16 + rq * 4 + reg;
        const int grow = rowsp[gi];
        const unsigned m = (unsigned)grow / 17u;
        const unsigned r = (unsigned)grow - m * 17u;
        const int gj = colBase + wcol0 + ni * 16 + fr;
        const int bb = gj >> 6;
        const int c = gj & 63;
        pkv[(((size_t)bb * NN + m) * NR + r) * 64 + c] = __float2bfloat16(acc[mi][ni][reg]);
      }
    }
  }
}

// ---------------- EI kernel: bf16 output, layout [t][ kg*64 + h*4 + (r&3) | 256 + h ] ----------------
__global__ __launch_bounds__(256) void ei_kernel(const float* __restrict__ ext,
                                                 const float* __restrict__ W1p,
                                                 const float* __restrict__ b1p,
                                                 const float* __restrict__ W2p,
                                                 const float* __restrict__ b2p,
                                                 const float* __restrict__ rbp,
                                                 const int* __restrict__ maskp,
                                                 __hip_bfloat16* __restrict__ EIF) {
  __shared__ float exts[64 * 21];
  __shared__ float W1s[64 * 21];
  __shared__ __hip_bfloat16 Hl[64 * 72];
  const int tid = threadIdx.x;
  const int tblk = blockIdx.x * 64;
  for (int i = tid; i < 64 * 21; i += 256) {
    exts[i] = ext[(size_t)tblk * 21 + i];
    W1s[i] = W1p[i];
  }
  __syncthreads();
  const int wave = tid >> 6, lane = tid & 63;
#pragma unroll
  for (int k = 0; k < 16; ++k) {
    const int tl = k * 4 + wave;
    float a = b1p[lane];
#pragma unroll
    for (int e = 0; e < 21; ++e) a += exts[tl * 21 + e] * W1s[lane * 21 + e];
    Hl[tl * 72 + lane] = __float2bfloat16(fmaxf(a, 0.f));
  }
  __syncthreads();
  const int fr = lane & 15, kg = lane >> 4;
  const __bf16* Hb = (const __bf16*)Hl;
  bf16x8 a0 = *(const bf16x8*)(Hb + (wave * 16 + fr) * 72 + kg * 8);
  bf16x8 a1 = *(const bf16x8*)(Hb + (wave * 16 + fr) * 72 + 32 + kg * 8);
#pragma unroll
  for (int tile = 0; tile < 9; ++tile) {
    const int o = tile * 16 + fr;
    bf16x8 bv0 = (bf16x8)f2b(0.0f), bv1 = (bf16x8)f2b(0.0f);
    if (o < 136) {
#pragma unroll
      for (int jj = 0; jj < 8; ++jj) {
        bv0[jj] = f2b(W2p[o * 64 + kg * 8 + jj]);
        bv1[jj] = f2b(W2p[o * 64 + 32 + kg * 8 + jj]);
      }
    }
    f32x4 acc = (f32x4)0.0f;
    acc = __builtin_amdgcn_mfma_f32_16x16x32_bf16(a0, bv0, acc, 0, 0, 0);
    acc = __builtin_amdgcn_mfma_f32_16x16x32_bf16(a1, bv1, acc, 0, 0, 0);
    if (o < 136) {
      const int h = (o * 241) >> 12;
      const int r = o - h * 17;
      const int noff = (r < 16) ? ((r >> 2) * 64 + h * 4 + (r & 3)) : (256 + h);
      const float rbo = rbp[o], b2o = b2p[o];
#pragma unroll
      for (int reg = 0; reg < 4; ++reg) {
        const int tl = tblk + wave * 16 + kg * 4 + reg;
        const int m = tl & (NN - 1);
        float v = maskp[m * NR + r] ? -1e30f : (rbo + 0.01f * (acc[reg] + b2o));
        EIF[(size_t)tl * 272 + noff] = __float2bfloat16(v);
      }
    }
  }
}

// ---------------- mega-fused attention v2: 16 tokens/block, swapped-QK softmax ----------------
__global__ __launch_bounds__(256, 4) void attn_mega(
    const __hip_bfloat16* __restrict__ XRp, const __hip_bfloat16* __restrict__ WQKp,
    const __hip_bfloat16* __restrict__ WVPp, const __hip_bfloat16* __restrict__ pkvB,
    const __hip_bfloat16* __restrict__ eifB, const float* __restrict__ bpp,
    float* __restrict__ outp) {
  __shared__ char qws[16 * 1024];
  __shared__ char Ts[16 * 1024];
  const int tid = threadIdx.x;
  const int wave = tid >> 6;
  const int lane = tid & 63;
  const int fr = lane & 15;
  const int kg = lane >> 4;
  const int h8 = fr & 7;
  const int t0 = blockIdx.x * 16;

  // ---- P0: qw_s = XR(tokens) @ WQK^T  (M=16, N=512, K=64) ----
  {
    bf16x8 a0 = *(const bf16x8*)((const __bf16*)XRp + (size_t)(t0 + fr) * 64 + kg * 8);
    bf16x8 a1 = *(const bf16x8*)((const __bf16*)XRp + (size_t)(t0 + fr) * 64 + 32 + kg * 8);
#pragma unroll
    for (int ci = 0; ci < 8; ++ci) {
      const int ct = wave * 8 + ci;
      f32x4 acc = (f32x4)0.0f;
      bf16x8 b0 = *(const bf16x8*)((const __bf16*)WQKp + (size_t)(ct * 16 + fr) * 64 + kg * 8);
      bf16x8 b1 =
          *(const bf16x8*)((const __bf16*)WQKp + (size_t)(ct * 16 + fr) * 64 + 32 + kg * 8);
      acc = __builtin_amdgcn_mfma_f32_16x16x32_bf16(a0, b0, acc, 0, 0, 0);
      acc = __builtin_amdgcn_mfma_f32_16x16x32_bf16(a1, b1, acc, 0, 0, 0);
#pragma unroll
      for (int reg = 0; reg < 4; ++reg) {
        const int row = kg * 4 + reg;
        const int col = ct * 16 + fr;
        *(__hip_bfloat16*)(qws + row * 1024 + SWZ(row, col * 2)) = __float2bfloat16(acc[reg]);
      }
    }
  }
  __syncthreads();

  // ---- token loop: 4 tokens per wave, prefetched ----
  {
    const __bf16* pk0 = (const __bf16*)pkvB + (size_t)(t0 + wave * 4) * 1088;
    bf16x8 nalo0 = *(const bf16x8*)(pk0 + fr * 64 + kg * 8);
    bf16x8 nalo1 = *(const bf16x8*)(pk0 + fr * 64 + 32 + kg * 8);
    bf16x8 nahi0 = *(const bf16x8*)(pk0 + (16 + fr) * 64 + kg * 8);
    bf16x8 nahi1 = *(const bf16x8*)(pk0 + (16 + fr) * 64 + 32 + kg * 8);

    for (int i = 0; i < 4; ++i) {
      const int tl = wave * 4 + i;
      const size_t tg = (size_t)t0 + tl;
      const __bf16* pk = (const __bf16*)pkvB + tg * 1088;

      bf16x8 alo0 = nalo0, alo1 = nalo1, ahi0 = nahi0, ahi1 = nahi1;
      if (i < 3) {
        const __bf16* pkn = pk + 1088;
        nalo0 = *(const bf16x8*)(pkn + fr * 64 + kg * 8);
        nalo1 = *(const bf16x8*)(pkn + fr * 64 + 32 + kg * 8);
        nahi0 = *(const bf16x8*)(pkn + (16 + fr) * 64 + kg * 8);
        nahi1 = *(const bf16x8*)(pkn + (16 + fr) * 64 + 32 + kg * 8);
      }

      // QK (swapped): D[r][h] = sum_c pkv[r][c] * qw[h][c]
      bf16x8 bq0 = *(const bf16x8*)(qws + tl * 1024 + (((h8 * 8 + kg) ^ (tl & 7)) << 4));
      bf16x8 bq1 = *(const bf16x8*)(qws + tl * 1024 + (((h8 * 8 + 4 + kg) ^ (tl & 7)) << 4));
      f32x4 slo = (f32x4)0.0f, shi = (f32x4)0.0f;
      slo = __builtin_amdgcn_mfma_f32_16x16x32_bf16(alo0, bq0, slo, 0, 0, 0);
      slo = __builtin_amdgcn_mfma_f32_16x16x32_bf16(alo1, bq1, slo, 0, 0, 0);
      shi = __builtin_amdgcn_mfma_f32_16x16x32_bf16(ahi0, bq0, shi, 0, 0, 0);
      shi = __builtin_amdgcn_mfma_f32_16x16x32_bf16(ahi1, bq1, shi, 0, 0, 0);

      // PV A-operand gather (issued early; latency hides under softmax):
      // av[j] = pkv[r=kg*8+j][c=ni*16+fr]  (r>16 garbage x zero-P, finite via pad)
      const __bf16* gb = pk + kg * 512 + fr;
      bf16x8 av0, av1, av2, av3;
#pragma unroll
      for (int j = 0; j < 8; ++j) {
        av0[j] = gb[j * 64];
        av1[j] = gb[j * 64 + 16];
        av2[j] = gb[j * 64 + 32];
        av3[j] = gb[j * 64 + 48];
      }

      // eif bias loads (bf16 layout [kg][h][reg] + [256+h])
      const __hip_bfloat16* eb = eifB + tg * 272;
      ushort4 ev = *(const ushort4*)((const unsigned short*)eb + kg * 64 + h8 * 4);
      const float ef0 = bf2f(__builtin_bit_cast(__hip_bfloat16, ev.x));
      const float ef1 = bf2f(__builtin_bit_cast(__hip_bfloat16, ev.y));
      const float ef2 = bf2f(__builtin_bit_cast(__hip_bfloat16, ev.z));
      const float ef3 = bf2f(__builtin_bit_cast(__hip_bfloat16, ev.w));
      const float e16v = bf2f(eb[256 + h8]);

      // softmax over r (regs + kg lanes + r16)
      const float s0 = slo[0] + ef0, s1 = slo[1] + ef1, s2 = slo[2] + ef2, s3 = slo[3] + ef3;
      const float s16 = shi[0] + e16v;
      float mx = fmaxf(fmaxf(s0, s1), fmaxf(s2, s3));
      mx = fmaxf(mx, (kg == 0) ? s16 : -3.0e38f);
      mx = fmaxf(mx, __shfl_xor(mx, 16));
      mx = fmaxf(mx, __shfl_xor(mx, 32));
      const float e0 = __expf(s0 - mx), e1 = __expf(s1 - mx);
      const float e2 = __expf(s2 - mx), e3 = __expf(s3 - mx);
      const float e16 = (kg == 0) ? __expf(s16 - mx) : 0.f;
      float sm = e0 + e1 + e2 + e3 + e16;
      sm += __shfl_xor(sm, 16);
      sm += __shfl_xor(sm, 32);
      const float iv = 1.0f / sm;

      // pack P and redistribute to PV B-fragment via shuffles
      const unsigned pk01 = pkbf(e0 * iv, e1 * iv);
      const unsigned pk23 = pkbf(e2 * iv, e3 * iv);
      const unsigned pk16 = pkbf(e16 * iv, 0.f);
      const int src0 = (fr + 32 * kg) & 63;
      const int src1 = (fr + 16 + 32 * kg) & 63;
      unsigned w0 = (unsigned)__shfl((int)pk01, src0);
      unsigned w1 = (unsigned)__shfl((int)pk23, src0);
      unsigned w2 = (unsigned)__shfl((int)pk01, src1);
      unsigned w3 = (unsigned)__shfl((int)pk23, src1);
      const unsigned w16 = (unsigned)__shfl((int)pk16, fr);
      if (kg == 2) { w0 = w16; w1 = 0; w2 = 0; w3 = 0; }
      if (kg == 3) { w0 = 0; w1 = 0; w2 = 0; w3 = 0; }
      uint4 apu;
      apu.x = w0; apu.y = w1; apu.z = w2; apu.w = w3;
      const bf16x8 ap = __builtin_bit_cast(bf16x8, apu);

      // PV (swapped): D[c][h]; write T rows packed (only h=fr<8 lanes)
#pragma unroll
      for (int ni = 0; ni < 4; ++ni) {
        const bf16x8 av = (ni == 0) ? av0 : (ni == 1) ? av1 : (ni == 2) ? av2 : av3;
        f32x4 o = __builtin_amdgcn_mfma_f32_16x16x32_bf16(av, ap, (f32x4)0.0f, 0, 0, 0);
        if (fr < 8) {
          uint2 val;
          val.x = pkbf(o[0], o[1]);
          val.y = pkbf(o[2], o[3]);
          const int byte = fr * 128 + ni * 32 + kg * 8;
          *(uint2*)(Ts + tl * 1024 + SWZ(tl, byte)) = val;
        }
      }
    }
  }
  __syncthreads();

  // ---- P2: out = T_s @ WVP^T + bp  (M=16 tokens, N=64, K=512); one col-tile per wave ----
  {
    const int ct = wave;
    f32x4 acc = (f32x4)0.0f;
#pragma unroll
    for (int kk = 0; kk < 16; ++kk) {
      bf16x8 a = *(const bf16x8*)(Ts + fr * 1024 + (((kk * 4 + kg) ^ (fr & 7)) << 4));
      bf16x8 b = *(const bf16x8*)((const __bf16*)WVPp + (size_t)(ct * 16 + fr) * 512 +
                                  kk * 32 + kg * 8);
      acc = __builtin_amdgcn_mfma_f32_16x16x32_bf16(a, b, acc, 0, 0, 0);
    }
    const float bpv = bpp[ct * 16 + fr];
#pragma unroll
    for (int reg = 0; reg < 4; ++reg)
      outp[(size_t)(t0 + kg * 4 + reg) * 64 + ct * 16 + fr] = acc[reg] + bpv;
  }
}

extern "C" void kernel_launch(void* const* d_in, const int* in_sizes, int n_in, void* d_out,
                              int out_size, void* d_ws, size_t ws_size, hipStream_t stream) {
  const float* x = (const float*)d_in[0];
  const float* ext = (const float*)d_in[1];
  const float* assign = (const float*)d_in[2];
  const float* Wq = (const float*)d_in[3];
  const float* Wkv = (const float*)d_in[4];
  const float* rb = (const float*)d_in[5];
  const float* W1 = (const float*)d_in[6];
  const float* b1 = (const float*)d_in[7];
  const float* W2 = (const float*)d_in[8];
  const float* b2 = (const float*)d_in[9];
  const float* Wp = (const float*)d_in[10];
  const float* bp = (const float*)d_in[11];
  const int* mask = (const int*)d_in[12];
  float* out = (float*)d_out;

  char* ws = (char*)d_ws;
  __hip_bfloat16* A2 = (__hip_bfloat16*)(ws + 0);            // 8,912,896
  __hip_bfloat16* WQK = (__hip_bfloat16*)(ws + 8912896);     // 65,536
  __hip_bfloat16* WVP = (__hip_bfloat16*)(ws + 8978432);     // 65,536
  __hip_bfloat16* XT = (__hip_bfloat16*)(ws + 9043968);      // 4,194,304
  __hip_bfloat16* XR = (__hip_bfloat16*)(ws + 13238272);     // 4,194,304
  __hip_bfloat16* PKV = (__hip_bfloat16*)(ws + 17432576);    // 71,303,168 + 8192 pad
  int* rowsBuf = (int*)(ws + 88743936);                      // 34,816
  int* metaBuf = (int*)(ws + 88778752);                      // 256
  __hip_bfloat16* EIF = (__hip_bfloat16*)(ws + 88779008);    // 17,825,792
  if (ws_size < (size_t)106604800) return;

  hipLaunchKernelGGL(pack_A, dim3(4, 512), dim3(256), 0, stream, assign, A2);
  hipLaunchKernelGGL(prep_w, dim3(64), dim3(256), 0, stream, Wq, Wkv, Wp, WQK, WVP);
  hipLaunchKernelGGL(pack_X, dim3(4, 64), dim3(256), 0, stream, x, XT, XR);
  hipLaunchKernelGGL(mask_scan, dim3(1), dim3(512), 0, stream, mask, rowsBuf, metaBuf);
  hipLaunchKernelGGL(gemm_prekv, dim3(32, 68), dim3(256), 0, stream, A2, XT, rowsBuf, metaBuf,
                     PKV);
  hipLaunchKernelGGL(ei_kernel, dim3(512), dim3(256), 0, stream, ext, W1, b1, W2, b2, rb, mask,
                     EIF);
  hipLaunchKernelGGL(attn_mega, dim3(2048), dim3(256), 0, stream, XR, WQK, WVP, PKV, EIF, bp,
                     out);
}